// Round 5
// baseline (150.978 us; speedup 1.0000x reference)
//
#include <hip/hip_runtime.h>
#include <hip/hip_bf16.h>
#include <math.h>

#define BB 16
#define CC 3
#define HH 336
#define WW 1078
#define HW (HH * WW)
#define TPR (WW / 2)           // threads per row, 2 px/thread = 539
#define NROWS (BB * HH)        // 5376
#define NTHREADS (NROWS * TPR) // 2,897,664 — divisible by 256 (11,319 blocks)

typedef float v2f __attribute__((ext_vector_type(2)));

// ---------------------------------------------------------------------------
// Kernel 1: closed-form DLT for the corner-rectangle case.
// src_pt rows are [0,0],[a,0],[0,b],[a,b] with a=W-1, b=H-1 (read at runtime).
// The 8x8 DLT system collapses:
//   h2=u0, h5=v0
//   a(u1-u3) h6 + b(u2-u3) h7 = u0-u1-u2+u3
//   a(v1-v3) h6 + b(v2-v3) h7 = v0-v1-v2+v3      (2x2 Cramer, f64)
//   h0=(u1-u0)/a + u1 h6   h1=(u2-u0)/b + u2 h7
//   h3=(v1-v0)/a + v1 h6   h4=(v2-v0)/b + v2 h7
// All static indexing -> pure registers, ~30 f64 ops.
// ---------------------------------------------------------------------------
__global__ void homography_kernel(const float* __restrict__ src_pt,
                                  const float* __restrict__ dst_pt,
                                  float* __restrict__ Hout) {
    int b = threadIdx.x;
    if (b >= BB) return;

    const float* s = src_pt + b * 8;
    const float* d = dst_pt + b * 8;
    double a  = (double)s[2];   // x of corner 1  (W-1)
    double bb = (double)s[5];   // y of corner 2  (H-1)
    double u0 = d[0], v0 = d[1], u1 = d[2], v1 = d[3];
    double u2 = d[4], v2 = d[5], u3 = d[6], v3 = d[7];

    double A11 = a  * (u1 - u3), A12 = bb * (u2 - u3), r1 = u0 - u1 - u2 + u3;
    double A21 = a  * (v1 - v3), A22 = bb * (v2 - v3), r2 = v0 - v1 - v2 + v3;
    double det = A11 * A22 - A12 * A21;
    double inv = 1.0 / det;
    double h6 = (r1 * A22 - A12 * r2) * inv;
    double h7 = (A11 * r2 - A21 * r1) * inv;

    double h0 = (u1 - u0) / a  + u1 * h6;
    double h1 = (u2 - u0) / bb + u2 * h7;
    double h3 = (v1 - v0) / a  + v1 * h6;
    double h4 = (v2 - v0) / bb + v2 * h7;

    float* Ho = Hout + b * 9;
    Ho[0] = (float)h0; Ho[1] = (float)h1; Ho[2] = (float)u0;
    Ho[3] = (float)h3; Ho[4] = (float)h4; Ho[5] = (float)v0;
    Ho[6] = (float)h6; Ho[7] = (float)h7; Ho[8] = 1.0f;
}

// ---------------------------------------------------------------------------
// Kernel 2: bilinear homography warp, 2 consecutive-x pixels per thread,
// all 3 channels, 8B nontemporal stores. Reference-exact f32 coordinate
// math (clipped-coordinate weights, |T|<1e-7 -> +1e-6 guard).
// ---------------------------------------------------------------------------
__global__ __launch_bounds__(256) void warp_kernel(const float* __restrict__ src,
                                                   const float* __restrict__ Hbuf,
                                                   float* __restrict__ out) {
    int t = blockIdx.x * 256 + threadIdx.x;   // grid is exact, no tail
    int xi2 = t % TPR;
    int row = t / TPR;
    int yi = row % HH;
    int b  = row / HH;
    int xi = xi2 * 2;

    const float* Hm = Hbuf + b * 9;
    float H0 = Hm[0], H1 = Hm[1], H2 = Hm[2];
    float H3 = Hm[3], H4 = Hm[4], H5 = Hm[5];
    float H6 = Hm[6], H7 = Hm[7], H8 = Hm[8];

    float gy = (float)yi;
    float Xy = H1 * gy + H2;
    float Yy = H4 * gy + H5;
    float Ty = H7 * gy + H8;

    const float* sb = src + b * CC * HW;
    float res[2][CC];

    #pragma unroll
    for (int j = 0; j < 2; ++j) {
        float gx = (float)(xi + j);
        float X = H0 * gx + Xy;
        float Y = H3 * gx + Yy;
        float T = H6 * gx + Ty;
        if (!(fabsf(T) >= 1e-7f)) T += 1e-6f;
        float x = X / T;
        float y = Y / T;

        float fx = floorf(x), fy = floorf(y);
        float x0 = fminf(fmaxf(fx,        0.0f), (float)(WW - 1));
        float x1 = fminf(fmaxf(fx + 1.0f, 0.0f), (float)(WW - 1));
        float y0 = fminf(fmaxf(fy,        0.0f), (float)(HH - 1));
        float y1 = fminf(fmaxf(fy + 1.0f, 0.0f), (float)(HH - 1));

        float wa = (x1 - x) * (y1 - y);
        float wb = (x1 - x) * (y - y0);
        float wc = (x - x0) * (y1 - y);
        float wd = (x - x0) * (y - y0);

        int ix0 = (int)x0, ix1 = (int)x1, iy0 = (int)y0, iy1 = (int)y1;
        int o00 = iy0 * WW + ix0;
        int o10 = iy1 * WW + ix0;
        int o01 = iy0 * WW + ix1;
        int o11 = iy1 * WW + ix1;

        #pragma unroll
        for (int c = 0; c < CC; ++c) {
            const float* sc = sb + c * HW;
            res[j][c] = wa * sc[o00] + wb * sc[o10] + wc * sc[o01] + wd * sc[o11];
        }
    }

    float* ob = out + b * CC * HW + yi * WW + xi;   // even offset -> 8B aligned
    #pragma unroll
    for (int c = 0; c < CC; ++c) {
        v2f v = { res[0][c], res[1][c] };
        __builtin_nontemporal_store(v, (v2f*)(ob + c * HW));
    }
}

extern "C" void kernel_launch(void* const* d_in, const int* in_sizes, int n_in,
                              void* d_out, int out_size, void* d_ws, size_t ws_size,
                              hipStream_t stream) {
    const float* src    = (const float*)d_in[0];
    const float* src_pt = (const float*)d_in[1];
    const float* dst_pt = (const float*)d_in[2];
    float* out = (float*)d_out;
    float* Hbuf = (float*)d_ws;  // 16 * 9 floats

    homography_kernel<<<1, 64, 0, stream>>>(src_pt, dst_pt, Hbuf);

    int blocks = NTHREADS / 256;  // 11,319 exactly
    warp_kernel<<<blocks, 256, 0, stream>>>(src, Hbuf, out);
}

// Round 6
// 133.746 us; speedup vs baseline: 1.1288x; 1.1288x over previous
//
#include <hip/hip_runtime.h>
#include <hip/hip_bf16.h>
#include <math.h>

#define BB 16
#define CC 3
#define HH 336
#define WW 1078
#define HW (HH * WW)
#define TPR (WW / 2)           // 539: thread t covers x=xi2 and x=xi2+539
#define NROWS (BB * HH)        // 5376
#define NTHREADS (NROWS * TPR) // 2,897,664 — divisible by 256 (11,319 blocks)

// ---------------------------------------------------------------------------
// Kernel 1: closed-form DLT for the corner-rectangle case (verified R5:
// dropped from 71.4 us to below top-5).
// src_pt rows are [0,0],[a,0],[0,b],[a,b] with a=W-1, b=H-1 (read at runtime).
//   h2=u0, h5=v0; 2x2 Cramer for (h6,h7); 4 substitutions. All registers.
// ---------------------------------------------------------------------------
__global__ void homography_kernel(const float* __restrict__ src_pt,
                                  const float* __restrict__ dst_pt,
                                  float* __restrict__ Hout) {
    int b = threadIdx.x;
    if (b >= BB) return;

    const float* s = src_pt + b * 8;
    const float* d = dst_pt + b * 8;
    double a  = (double)s[2];   // x of corner 1  (W-1)
    double bb = (double)s[5];   // y of corner 2  (H-1)
    double u0 = d[0], v0 = d[1], u1 = d[2], v1 = d[3];
    double u2 = d[4], v2 = d[5], u3 = d[6], v3 = d[7];

    double A11 = a  * (u1 - u3), A12 = bb * (u2 - u3), r1 = u0 - u1 - u2 + u3;
    double A21 = a  * (v1 - v3), A22 = bb * (v2 - v3), r2 = v0 - v1 - v2 + v3;
    double det = A11 * A22 - A12 * A21;
    double inv = 1.0 / det;
    double h6 = (r1 * A22 - A12 * r2) * inv;
    double h7 = (A11 * r2 - A21 * r1) * inv;

    double h0 = (u1 - u0) / a  + u1 * h6;
    double h1 = (u2 - u0) / bb + u2 * h7;
    double h3 = (v1 - v0) / a  + v1 * h6;
    double h4 = (v2 - v0) / bb + v2 * h7;

    float* Ho = Hout + b * 9;
    Ho[0] = (float)h0; Ho[1] = (float)h1; Ho[2] = (float)u0;
    Ho[3] = (float)h3; Ho[4] = (float)h4; Ho[5] = (float)v0;
    Ho[6] = (float)h6; Ho[7] = (float)h7; Ho[8] = 1.0f;
}

// ---------------------------------------------------------------------------
// Kernel 2: bilinear homography warp. 2 pixels per thread, FAR-SPLIT:
// thread handles x=xi2 and x=xi2+539 so that for each j, consecutive lanes
// access consecutive addresses (full coalescing — R5's adjacent-pair split
// was a stride-2 gather and regressed 45->65 us). 24 independent loads in
// flight per thread for latency hiding. Plain coalesced 4B stores.
// Reference-exact f32 coordinate math (clipped-coordinate weights,
// |T|<1e-7 -> +1e-6 guard).
// ---------------------------------------------------------------------------
__global__ __launch_bounds__(256) void warp_kernel(const float* __restrict__ src,
                                                   const float* __restrict__ Hbuf,
                                                   float* __restrict__ out) {
    int t = blockIdx.x * 256 + threadIdx.x;   // grid is exact, no tail
    int xi2 = t % TPR;
    int row = t / TPR;
    int yi = row % HH;
    int b  = row / HH;

    const float* Hm = Hbuf + b * 9;
    float H0 = Hm[0], H1 = Hm[1], H2 = Hm[2];
    float H3 = Hm[3], H4 = Hm[4], H5 = Hm[5];
    float H6 = Hm[6], H7 = Hm[7], H8 = Hm[8];

    float gy = (float)yi;
    float Xy = H1 * gy + H2;
    float Yy = H4 * gy + H5;
    float Ty = H7 * gy + H8;

    const float* sb = src + b * CC * HW;
    float res[2][CC];

    #pragma unroll
    for (int j = 0; j < 2; ++j) {
        float gx = (float)(xi2 + j * TPR);
        float X = H0 * gx + Xy;
        float Y = H3 * gx + Yy;
        float T = H6 * gx + Ty;
        if (!(fabsf(T) >= 1e-7f)) T += 1e-6f;
        float x = X / T;
        float y = Y / T;

        float fx = floorf(x), fy = floorf(y);
        float x0 = fminf(fmaxf(fx,        0.0f), (float)(WW - 1));
        float x1 = fminf(fmaxf(fx + 1.0f, 0.0f), (float)(WW - 1));
        float y0 = fminf(fmaxf(fy,        0.0f), (float)(HH - 1));
        float y1 = fminf(fmaxf(fy + 1.0f, 0.0f), (float)(HH - 1));

        float wa = (x1 - x) * (y1 - y);
        float wb = (x1 - x) * (y - y0);
        float wc = (x - x0) * (y1 - y);
        float wd = (x - x0) * (y - y0);

        int ix0 = (int)x0, ix1 = (int)x1, iy0 = (int)y0, iy1 = (int)y1;
        int o00 = iy0 * WW + ix0;
        int o10 = iy1 * WW + ix0;
        int o01 = iy0 * WW + ix1;
        int o11 = iy1 * WW + ix1;

        #pragma unroll
        for (int c = 0; c < CC; ++c) {
            const float* sc = sb + c * HW;
            res[j][c] = wa * sc[o00] + wb * sc[o10] + wc * sc[o01] + wd * sc[o11];
        }
    }

    float* ob = out + b * CC * HW + yi * WW + xi2;
    #pragma unroll
    for (int c = 0; c < CC; ++c) {
        ob[c * HW]       = res[0][c];
        ob[c * HW + TPR] = res[1][c];
    }
}

extern "C" void kernel_launch(void* const* d_in, const int* in_sizes, int n_in,
                              void* d_out, int out_size, void* d_ws, size_t ws_size,
                              hipStream_t stream) {
    const float* src    = (const float*)d_in[0];
    const float* src_pt = (const float*)d_in[1];
    const float* dst_pt = (const float*)d_in[2];
    float* out = (float*)d_out;
    float* Hbuf = (float*)d_ws;  // 16 * 9 floats

    homography_kernel<<<1, 64, 0, stream>>>(src_pt, dst_pt, Hbuf);

    int blocks = NTHREADS / 256;  // 11,319 exactly
    warp_kernel<<<blocks, 256, 0, stream>>>(src, Hbuf, out);
}